// Round 2
// baseline (876.201 us; speedup 1.0000x reference)
//
#include <hip/hip_runtime.h>

typedef unsigned short u16;
typedef unsigned int   u32;

using bf16x8 = __attribute__((ext_vector_type(8))) short;  // 8 bf16 in 4 VGPRs
using f32x4  = __attribute__((ext_vector_type(4))) float;

__device__ __forceinline__ float bf2f(u16 h) {
  u32 u = ((u32)h) << 16;
  return __builtin_bit_cast(float, u);
}
__device__ __forceinline__ u16 f2bf(float f) {   // round-to-nearest-even
  u32 u = __builtin_bit_cast(u32, f);
  u += 0x7fffu + ((u >> 16) & 1u);
  return (u16)(u >> 16);
}

__device__ __forceinline__ void gload16(const u16* src, u16* ldsdst) {
  __builtin_amdgcn_global_load_lds(
      (const __attribute__((address_space(1))) void*)src,
      (__attribute__((address_space(3))) void*)ldsdst, 16, 0, 0);
}

// ---------------------------------------------------------------------------
// f32 -> bf16 weight conversion, 8 elems/thread
__global__ __launch_bounds__(256) void cvt_bf16(const float* __restrict__ in,
                                                u16* __restrict__ out, int n8) {
  int i = blockIdx.x * 256 + threadIdx.x;
  if (i >= n8) return;
  const float* p = in + (size_t)i * 8;
  bf16x8 o;
#pragma unroll
  for (int j = 0; j < 8; ++j) o[j] = (short)f2bf(p[j]);
  *(bf16x8*)(out + (size_t)i * 8) = o;
}

// ---------------------------------------------------------------------------
// h[m, d] = relu(x[b, f] * W[f, d] + bias[f, d]), m = bc*F + f (chunk-local)
__global__ __launch_bounds__(256) void hgen(const float* __restrict__ x,
                                            const float* __restrict__ W,
                                            const float* __restrict__ bias,
                                            u16* __restrict__ h, int F, int logF,
                                            int b0, int xstride, int total8) {
  int idx = blockIdx.x * 256 + threadIdx.x;
  if (idx >= total8) return;
  int d0 = (idx & 127) << 3;
  int m  = idx >> 7;
  int f  = m & (F - 1);
  int b  = b0 + (m >> logF);
  float xv = x[(size_t)b * xstride + f];
  const float* wp = W + (size_t)f * 1024 + d0;
  const float* bp = bias + (size_t)f * 1024 + d0;
  bf16x8 o;
#pragma unroll
  for (int j = 0; j < 8; ++j) o[j] = (short)f2bf(fmaxf(xv * wp[j] + bp[j], 0.f));
  *(bf16x8*)(h + (size_t)m * 1024 + d0) = o;
}

// ---------------------------------------------------------------------------
// C(MxN, bf16) = A(MxK, bf16) * B^T (B stored NxK, bf16) + bias(N, f32)
// 128x128 tile, BK=64, 4 waves (2x2), m97 structure:
// global_load_lds width 16, XOR slot swizzle via pre-swizzled global source.
// M%128==0, N%128==0, K%64==0 required.
__global__ __launch_bounds__(256) void gemm_bt(const u16* __restrict__ A,
                                               const u16* __restrict__ B,
                                               const float* __restrict__ bias,
                                               u16* __restrict__ C,
                                               int M, int N, int K) {
  __shared__ u16 As[128 * 64];
  __shared__ u16 Bs[128 * 64];
  const int tid  = threadIdx.x;
  const int lane = tid & 63;
  const int w    = tid >> 6;
  const int wm   = w >> 1, wn = w & 1;
  const int m0 = blockIdx.y * 128;
  const int n0 = blockIdx.x * 128;

  f32x4 acc[4][4] = {};

  // staging constants: each gload16 covers 8 rows (64 bf16 = 8 slots of 16B/row)
  const int r_in  = lane >> 3;                 // row within 8-row chunk
  const int s_log = (lane & 7) ^ r_in;         // logical 16B slot to fetch (XOR swizzle)

  for (int k0 = 0; k0 < K; k0 += 64) {
#pragma unroll
    for (int cc = 0; cc < 4; ++cc) {
      int chunk = w * 4 + cc;                  // wave-uniform
      int r = chunk * 8 + r_in;
      gload16(A + (size_t)(m0 + r) * K + k0 + s_log * 8, As + chunk * 512);
      gload16(B + (size_t)(n0 + r) * K + k0 + s_log * 8, Bs + chunk * 512);
    }
    __syncthreads();
#pragma unroll
    for (int kk = 0; kk < 2; ++kk) {
      bf16x8 af[4], bg[4];
      const int sl = kk * 4 + (lane >> 4);
#pragma unroll
      for (int i = 0; i < 4; ++i) {
        int ra = wm * 64 + i * 16 + (lane & 15);
        af[i] = *(const bf16x8*)(As + ra * 64 + (sl ^ (ra & 7)) * 8);
        int rb = wn * 64 + i * 16 + (lane & 15);
        bg[i] = *(const bf16x8*)(Bs + rb * 64 + (sl ^ (rb & 7)) * 8);
      }
#pragma unroll
      for (int i = 0; i < 4; ++i)
#pragma unroll
        for (int j = 0; j < 4; ++j)
          acc[i][j] = __builtin_amdgcn_mfma_f32_16x16x32_bf16(af[i], bg[j], acc[i][j], 0, 0, 0);
    }
    __syncthreads();
  }

  // epilogue: D layout col = lane&15, row = (lane>>4)*4 + reg
#pragma unroll
  for (int j = 0; j < 4; ++j) {
    int cl = n0 + wn * 64 + j * 16 + (lane & 15);
    float bsv = bias[cl];
#pragma unroll
    for (int i = 0; i < 4; ++i) {
      int r0 = m0 + wm * 64 + i * 16 + (lane >> 4) * 4;
#pragma unroll
      for (int reg = 0; reg < 4; ++reg)
        C[(size_t)(r0 + reg) * N + cl] = f2bf(acc[i][j][reg] + bsv);
    }
  }
}

// ---------------------------------------------------------------------------
// Fused attention for one (chunk-batch bc, head, 64-row q-block).
// qkv: (Bc*F, 3072) bf16 rows [q | k | v]; o_out: (Bc*F, 1024) bf16.
// Per wave: 16 q-rows. Swapped QK^T (S^T = K*Q^T) so softmax row state is
// per-lane (qrow = lane&15); P transposed through wave-private padded LDS so
// PV reuses mfma_f32_16x16x32_bf16 with A=P, B=v^T.
__global__ __launch_bounds__(256) void attn(const u16* __restrict__ qkv,
                                            u16* __restrict__ o_out, int F) {
  __shared__ u16 q_lds[64 * 136];   // [64][128+8]
  __shared__ u16 k_lds[64 * 136];
  __shared__ u16 vT[128 * 72];      // [128 d][64+8 kpos]
  __shared__ u16 p_lds[4 * 16 * 72];// per-wave [16 qrow][64+8 kpos]

  const int tid  = threadIdx.x;
  const int lane = tid & 63;
  const int w    = tid >> 6;
  const int bc = blockIdx.z, head = blockIdx.y, qb = blockIdx.x;
  const size_t rowbase = (size_t)bc * F * 3072;
  const float scale = 0.08838834764831845f;   // 1/sqrt(128)

  // stage q (scaled by 1/sqrt(Dh))
  {
    const u16* qsrc = qkv + rowbase + (size_t)(qb * 64) * 3072 + head * 128;
    for (int it = tid; it < 1024; it += 256) {
      int r = it >> 4, s = it & 15;
      bf16x8 v = *(const bf16x8*)(qsrc + (size_t)r * 3072 + s * 8);
      bf16x8 o;
#pragma unroll
      for (int j = 0; j < 8; ++j) o[j] = (short)f2bf(bf2f((u16)v[j]) * scale);
      *(bf16x8*)(q_lds + r * 136 + s * 8) = o;
    }
  }

  f32x4 o_acc[8] = {};
  float m_run = -INFINITY, l_run = 0.f;
  const int qr = lane & 15;   // this lane's qrow (softmax state owner)
  const int g4 = lane >> 4;

  const int nkb = F >> 6;
  for (int kb = 0; kb < nkb; ++kb) {
    __syncthreads();   // protect k_lds/vT reuse (and q staging on kb==0)
    const u16* ksrc = qkv + rowbase + (size_t)(kb * 64) * 3072 + 1024 + head * 128;
    const u16* vsrc = qkv + rowbase + (size_t)(kb * 64) * 3072 + 2048 + head * 128;
    for (int it = tid; it < 1024; it += 256) {
      int r = it >> 4, s = it & 15;
      *(bf16x8*)(k_lds + r * 136 + s * 8) = *(const bf16x8*)(ksrc + (size_t)r * 3072 + s * 8);
      bf16x8 v = *(const bf16x8*)(vsrc + (size_t)r * 3072 + s * 8);
      int d0 = s * 8;
#pragma unroll
      for (int j = 0; j < 8; ++j) vT[(d0 + j) * 72 + r] = (u16)v[j];
    }
    __syncthreads();

    // S^T (64 kpos x 16 qrows): A = k rows, B = q^T
    f32x4 sa[4] = {};
#pragma unroll
    for (int kk = 0; kk < 4; ++kk) {
      bf16x8 bq = *(const bf16x8*)(q_lds + (w * 16 + qr) * 136 + kk * 32 + 8 * g4);
#pragma unroll
      for (int f = 0; f < 4; ++f) {
        bf16x8 ak = *(const bf16x8*)(k_lds + (f * 16 + qr) * 136 + kk * 32 + 8 * g4);
        sa[f] = __builtin_amdgcn_mfma_f32_16x16x32_bf16(ak, bq, sa[f], 0, 0, 0);
      }
    }

    // online softmax: lane holds S^T[kpos = f*16 + g4*4 + reg][qrow = qr]
    float tmax = -INFINITY;
#pragma unroll
    for (int f = 0; f < 4; ++f)
#pragma unroll
      for (int rr = 0; rr < 4; ++rr) tmax = fmaxf(tmax, sa[f][rr]);
    tmax = fmaxf(tmax, __shfl_xor(tmax, 16));
    tmax = fmaxf(tmax, __shfl_xor(tmax, 32));
    float mnew  = fmaxf(m_run, tmax);
    float alpha = __expf(m_run - mnew);
    float psum  = 0.f;
#pragma unroll
    for (int f = 0; f < 4; ++f) {
      u16 pp[4];
#pragma unroll
      for (int rr = 0; rr < 4; ++rr) {
        float p = __expf(sa[f][rr] - mnew);
        psum += p;
        pp[rr] = f2bf(p);
      }
      uint2 u;
      u.x = (u32)pp[0] | ((u32)pp[1] << 16);
      u.y = (u32)pp[2] | ((u32)pp[3] << 16);
      *(uint2*)(p_lds + w * 1152 + qr * 72 + f * 16 + g4 * 4) = u;  // P[qrow][kpos]
    }
    psum += __shfl_xor(psum, 16);
    psum += __shfl_xor(psum, 32);
    l_run = l_run * alpha + psum;
    m_run = mnew;

    // rescale o_acc: its qrow = g4*4+reg, alpha lives in lane (g4*4+reg)
#pragma unroll
    for (int rr = 0; rr < 4; ++rr) {
      float ar = __shfl(alpha, g4 * 4 + rr);
#pragma unroll
      for (int g = 0; g < 8; ++g) o_acc[g][rr] *= ar;
    }

    // PV: o[qrow, d] += P[qrow, kpos] * v[kpos, d]
#pragma unroll
    for (int kk2 = 0; kk2 < 2; ++kk2) {
      bf16x8 pa = *(const bf16x8*)(p_lds + w * 1152 + qr * 72 + kk2 * 32 + 8 * g4);
#pragma unroll
      for (int g = 0; g < 8; ++g) {
        bf16x8 vb = *(const bf16x8*)(vT + (g * 16 + qr) * 72 + kk2 * 32 + 8 * g4);
        o_acc[g] = __builtin_amdgcn_mfma_f32_16x16x32_bf16(pa, vb, o_acc[g], 0, 0, 0);
      }
    }
  }

  float linv = 1.f / l_run;
#pragma unroll
  for (int rr = 0; rr < 4; ++rr) {
    float lr = __shfl(linv, g4 * 4 + rr);
    size_t row = (size_t)bc * F + qb * 64 + w * 16 + g4 * 4 + rr;
#pragma unroll
    for (int g = 0; g < 8; ++g)
      o_out[row * 1024 + head * 128 + g * 16 + qr] = f2bf(o_acc[g][rr] * lr);
  }
}

// ---------------------------------------------------------------------------
// per-row LayerNorm stats: one wave per row of 1024 bf16
__global__ __launch_bounds__(256) void ln_stats(const u16* __restrict__ proj,
                                                float2* __restrict__ stats) {
  int row  = blockIdx.x * 4 + (threadIdx.x >> 6);
  int lane = threadIdx.x & 63;
  const u16* p = proj + (size_t)row * 1024;
  float s = 0.f, s2 = 0.f;
#pragma unroll
  for (int i = 0; i < 2; ++i) {
    bf16x8 v = *(const bf16x8*)(p + (lane + i * 64) * 8);
#pragma unroll
    for (int j = 0; j < 8; ++j) { float f = bf2f((u16)v[j]); s += f; s2 += f * f; }
  }
#pragma unroll
  for (int m = 1; m < 64; m <<= 1) { s += __shfl_xor(s, m); s2 += __shfl_xor(s2, m); }
  if (lane == 0) {
    float mu  = s * (1.f / 1024.f);
    float var = s2 * (1.f / 1024.f) - mu * mu;
    stats[row] = make_float2(mu, rsqrtf(var + 1e-5f));
  }
}

// LN apply + sum over 64 f-rows, atomic into dp[b, d]
__global__ __launch_bounds__(256) void ln_accum(const u16* __restrict__ proj,
                                                const float2* __restrict__ stats,
                                                const float* __restrict__ g,
                                                const float* __restrict__ beta,
                                                float* __restrict__ dp, int F, int b0) {
  int d  = blockIdx.x * 256 + threadIdx.x;
  int bc = blockIdx.z;
  int f0 = blockIdx.y * 64;
  const u16* base = proj + ((size_t)(bc * F + f0)) * 1024 + d;
  const float2* st = stats + bc * F + f0;
  float acc = 0.f;
  for (int f = 0; f < 64; ++f) {
    float2 s = st[f];
    acc += (bf2f(base[(size_t)f * 1024]) - s.x) * s.y;
  }
  acc = acc * g[d] + 64.f * beta[d];
  atomicAdd(&dp[(size_t)(b0 + bc) * 1024 + d], acc);
}

// cosine similarity + sigmoid, one block per batch element
__global__ __launch_bounds__(256) void cosine_sig(const float* __restrict__ dp,
                                                  const float* __restrict__ tp,
                                                  float* __restrict__ out) {
  __shared__ float red[3][4];
  int b = blockIdx.x;
  int tid = threadIdx.x, lane = tid & 63, w = tid >> 6;
  float dot = 0.f, n1 = 0.f, n2 = 0.f;
  for (int i = tid; i < 1024; i += 256) {
    float a = dp[(size_t)b * 1024 + i], c = tp[(size_t)b * 1024 + i];
    dot += a * c; n1 += a * a; n2 += c * c;
  }
#pragma unroll
  for (int m = 1; m < 64; m <<= 1) {
    dot += __shfl_xor(dot, m); n1 += __shfl_xor(n1, m); n2 += __shfl_xor(n2, m);
  }
  if (lane == 0) { red[0][w] = dot; red[1][w] = n1; red[2][w] = n2; }
  __syncthreads();
  if (tid == 0) {
    dot = red[0][0] + red[0][1] + red[0][2] + red[0][3];
    n1  = red[1][0] + red[1][1] + red[1][2] + red[1][3];
    n2  = red[2][0] + red[2][1] + red[2][2] + red[2][3];
    float denom = fmaxf(sqrtf(n1) * sqrtf(n2), 1e-8f);
    out[b] = 1.f / (1.f + __expf(-dot / denom));
  }
}

// ---------------------------------------------------------------------------
extern "C" void kernel_launch(void* const* d_in, const int* in_sizes, int n_in,
                              void* d_out, int out_size, void* d_ws, size_t ws_size,
                              hipStream_t stream) {
  const float* drug   = (const float*)d_in[0];
  const float* target = (const float*)d_in[1];

  char* p = (char*)d_ws;
  auto alloc = [&](size_t bytes) -> char* {
    char* r = p; p += (bytes + 255) & ~(size_t)255; return r;
  };

  u16* w_in_d  = (u16*)alloc((size_t)3072 * 1024 * 2);
  u16* w_out_d = (u16*)alloc((size_t)1024 * 1024 * 2);
  u16* w_in_t  = (u16*)alloc((size_t)3072 * 1024 * 2);
  u16* w_out_t = (u16*)alloc((size_t)1024 * 1024 * 2);
  float* dp    = (float*)alloc((size_t)2 * 128 * 1024 * 4);
  float* tp    = dp + 128 * 1024;

  // chunk size: largest Bc whose scratch fits in ws
  size_t fixed = (size_t)(p - (char*)d_ws);
  size_t per = (size_t)256 * 1024 * 2 * 3   /* h, o, proj */
             + (size_t)256 * 3072 * 2       /* qkv */
             + (size_t)256 * 8 + 2048;      /* stats + align slack */
  int Bc = 8;
  if      (fixed + 128 * per <= ws_size) Bc = 128;
  else if (fixed +  64 * per <= ws_size) Bc = 64;
  else if (fixed +  32 * per <= ws_size) Bc = 32;
  else if (fixed +  16 * per <= ws_size) Bc = 16;

  u16* hbuf    = (u16*)alloc((size_t)Bc * 256 * 1024 * 2);
  u16* qkvbuf  = (u16*)alloc((size_t)Bc * 256 * 3072 * 2);
  u16* obuf    = (u16*)alloc((size_t)Bc * 256 * 1024 * 2);
  u16* projbuf = (u16*)alloc((size_t)Bc * 256 * 1024 * 2);
  float2* statsb = (float2*)alloc((size_t)Bc * 256 * 8);

  cvt_bf16<<<1536, 256, 0, stream>>>((const float*)d_in[4],  w_in_d,  3072 * 128);
  cvt_bf16<<<512,  256, 0, stream>>>((const float*)d_in[6],  w_out_d, 1024 * 128);
  cvt_bf16<<<1536, 256, 0, stream>>>((const float*)d_in[12], w_in_t,  3072 * 128);
  cvt_bf16<<<512,  256, 0, stream>>>((const float*)d_in[14], w_out_t, 1024 * 128);
  hipMemsetAsync(dp, 0, (size_t)2 * 128 * 1024 * 4, stream);

  for (int br = 0; br < 2; ++br) {
    const int F = br ? 128 : 256, logF = br ? 7 : 8, xstride = br ? 1024 : 2048;
    const float* x    = br ? target : drug;
    const float* W    = (const float*)d_in[br ? 10 : 2];
    const float* Wb   = (const float*)d_in[br ? 11 : 3];
    u16*         win  = br ? w_in_t : w_in_d;
    const float* inb  = (const float*)d_in[br ? 13 : 5];
    u16*         wout = br ? w_out_t : w_out_d;
    const float* outb = (const float*)d_in[br ? 15 : 7];
    const float* gg   = (const float*)d_in[br ? 16 : 8];
    const float* bb   = (const float*)d_in[br ? 17 : 9];
    float*       accp = br ? tp : dp;

    for (int b0 = 0; b0 < 128; b0 += Bc) {
      const int Mr = Bc * F;
      hgen<<<Mr * 128 / 256, 256, 0, stream>>>(x, W, Wb, hbuf, F, logF, b0, xstride, Mr * 128);
      gemm_bt<<<dim3(3072 / 128, Mr / 128), 256, 0, stream>>>(hbuf, win, inb, qkvbuf, Mr, 3072, 1024);
      attn<<<dim3(F / 64, 8, Bc), 256, 0, stream>>>(qkvbuf, obuf, F);
      gemm_bt<<<dim3(1024 / 128, Mr / 128), 256, 0, stream>>>(obuf, wout, outb, projbuf, Mr, 1024, 1024);
      ln_stats<<<Mr / 4, 256, 0, stream>>>(projbuf, statsb);
      ln_accum<<<dim3(4, F / 64, Bc), 256, 0, stream>>>(projbuf, statsb, gg, bb, accp, F, b0);
    }
  }
  cosine_sig<<<128, 256, 0, stream>>>(dp, tp, (float*)d_out);
}

// Round 3
// 854.939 us; speedup vs baseline: 1.0249x; 1.0249x over previous
//
#include <hip/hip_runtime.h>

typedef unsigned short u16;
typedef unsigned int   u32;

using bf16x8 = __attribute__((ext_vector_type(8))) short;  // 8 bf16 in 4 VGPRs
using f32x4  = __attribute__((ext_vector_type(4))) float;

__device__ __forceinline__ float bf2f(u16 h) {
  u32 u = ((u32)h) << 16;
  return __builtin_bit_cast(float, u);
}
__device__ __forceinline__ u16 f2bf(float f) {   // round-to-nearest-even
  u32 u = __builtin_bit_cast(u32, f);
  u += 0x7fffu + ((u >> 16) & 1u);
  return (u16)(u >> 16);
}

__device__ __forceinline__ void gload16(const u16* src, u16* ldsdst) {
  __builtin_amdgcn_global_load_lds(
      (const __attribute__((address_space(1))) void*)src,
      (__attribute__((address_space(3))) void*)ldsdst, 16, 0, 0);
}

// ---------------------------------------------------------------------------
// f32 -> bf16 weight conversion, 8 elems/thread
__global__ __launch_bounds__(256) void cvt_bf16(const float* __restrict__ in,
                                                u16* __restrict__ out, int n8) {
  int i = blockIdx.x * 256 + threadIdx.x;
  if (i >= n8) return;
  const float* p = in + (size_t)i * 8;
  bf16x8 o;
#pragma unroll
  for (int j = 0; j < 8; ++j) o[j] = (short)f2bf(p[j]);
  *(bf16x8*)(out + (size_t)i * 8) = o;
}

// ---------------------------------------------------------------------------
// h[m, d] = relu(x[b, f] * W[f, d] + bias[f, d]), m = bc*F + f (chunk-local)
__global__ __launch_bounds__(256) void hgen(const float* __restrict__ x,
                                            const float* __restrict__ W,
                                            const float* __restrict__ bias,
                                            u16* __restrict__ h, int F, int logF,
                                            int b0, int xstride, int total8) {
  int idx = blockIdx.x * 256 + threadIdx.x;
  if (idx >= total8) return;
  int d0 = (idx & 127) << 3;
  int m  = idx >> 7;
  int f  = m & (F - 1);
  int b  = b0 + (m >> logF);
  float xv = x[(size_t)b * xstride + f];
  const float* wp = W + (size_t)f * 1024 + d0;
  const float* bp = bias + (size_t)f * 1024 + d0;
  bf16x8 o;
#pragma unroll
  for (int j = 0; j < 8; ++j) o[j] = (short)f2bf(fmaxf(xv * wp[j] + bp[j], 0.f));
  *(bf16x8*)(h + (size_t)m * 1024 + d0) = o;
}

// ---------------------------------------------------------------------------
// C(MxN, bf16) = A(MxK, bf16) * B^T (B stored NxK) + bias(N, f32)
// 256x128 tile, BK=64, 8 waves (4m x 2n), TRIPLE-buffered LDS deep pipeline:
//   iter kt: stage kt+2 -> buf[(kt+2)%3]  (WAR-free: last read of that buffer
//            finished before the PREVIOUS barrier)
//            ds_read frags of kt; 32 MFMA; s_waitcnt vmcnt(6); s_barrier
// Counted vmcnt (T4): the 6 loads of kt+2 stay in flight across the barrier.
// Requires M%256==0, N%128==0, K%128==0, NT>=2.
__global__ __launch_bounds__(512, 2) void gemm256(const u16* __restrict__ A,
                                                  const u16* __restrict__ B,
                                                  const float* __restrict__ bias,
                                                  u16* __restrict__ C,
                                                  int M, int N, int K) {
  __shared__ u16 lds3[3 * 24576];   // 3 x (A 256x64 + B 128x64) = 144 KiB
  const int tid  = threadIdx.x;
  const int lane = tid & 63;
  const int w    = tid >> 6;
  const int wm   = w >> 1;          // 0..3 : 64-row group
  const int wn   = w & 1;           // 0..1 : 64-col group

  // bijective XCD swizzle (m204)
  const int nwg = gridDim.x * gridDim.y;
  const int wg  = blockIdx.y * gridDim.x + blockIdx.x;
  const int q = nwg >> 3, r = nwg & 7, xcd = wg & 7, loc = wg >> 3;
  const int swz = (xcd < r ? xcd * (q + 1) : r * (q + 1) + (xcd - r) * q) + loc;
  const int n0 = (swz % gridDim.x) * 128;
  const int m0 = (swz / gridDim.x) * 256;

  f32x4 acc[4][4] = {};

  const int r_in  = lane >> 3;             // row within 8-row chunk
  const int s_log = (lane & 7) ^ r_in;     // pre-swizzled 16B slot to fetch

  // stage one K-tile (A 256x64 + B 128x64) into buf; 6 gload16 per wave
  auto stage = [&](int k0, u16* buf) {
#pragma unroll
    for (int i = 0; i < 4; ++i) {          // A chunks c = w + i*8 (0..31)
      int rr = w * 8 + i * 64 + r_in;
      gload16(A + (size_t)(m0 + rr) * K + k0 + s_log * 8, buf + (w + i * 8) * 512);
    }
#pragma unroll
    for (int i = 0; i < 2; ++i) {          // B chunks c = w + i*8 (0..15)
      int rr = w * 8 + i * 64 + r_in;
      gload16(B + (size_t)(n0 + rr) * K + k0 + s_log * 8, buf + 16384 + (w + i * 8) * 512);
    }
  };

  const int NT = K >> 6;
  // prologue: stage kt0, kt1; wait kt0 landed (own 6 of 12 outstanding)
  stage(0, lds3);
  stage(64, lds3 + 24576);
  asm volatile("s_waitcnt vmcnt(6)" ::: "memory");
  __builtin_amdgcn_s_barrier();
  __builtin_amdgcn_sched_barrier(0);

  int cur = 0, nxt = 2;
  for (int kt = 0; kt < NT; ++kt) {
    if (kt + 2 < NT) stage((kt + 2) << 6, lds3 + nxt * 24576);

    const u16* bufc = lds3 + cur * 24576;
    bf16x8 af[4][2], bg[4][2];
#pragma unroll
    for (int kk = 0; kk < 2; ++kk) {
      const int sl = kk * 4 + (lane >> 4);
#pragma unroll
      for (int mf = 0; mf < 4; ++mf) {
        int ra = wm * 64 + mf * 16 + (lane & 15);
        af[mf][kk] = *(const bf16x8*)(bufc + ra * 64 + (sl ^ (ra & 7)) * 8);
      }
#pragma unroll
      for (int nf = 0; nf < 4; ++nf) {
        int rb = wn * 64 + nf * 16 + (lane & 15);
        bg[nf][kk] = *(const bf16x8*)(bufc + 16384 + rb * 64 + (sl ^ (rb & 7)) * 8);
      }
    }
#pragma unroll
    for (int mf = 0; mf < 4; ++mf)
#pragma unroll
      for (int nf = 0; nf < 4; ++nf)
#pragma unroll
        for (int kk = 0; kk < 2; ++kk)
          acc[mf][nf] = __builtin_amdgcn_mfma_f32_16x16x32_bf16(af[mf][kk], bg[nf][kk], acc[mf][nf], 0, 0, 0);

    // counted wait: keep kt+2's 6 loads in flight; drain only at the tail
    if (kt + 2 < NT) asm volatile("s_waitcnt vmcnt(6)" ::: "memory");
    else             asm volatile("s_waitcnt vmcnt(0)" ::: "memory");
    __builtin_amdgcn_s_barrier();
    __builtin_amdgcn_sched_barrier(0);

    cur = (cur == 2) ? 0 : cur + 1;
    nxt = (nxt == 2) ? 0 : nxt + 1;
  }

  // epilogue: D layout col = lane&15, row = (lane>>4)*4 + reg
#pragma unroll
  for (int nf = 0; nf < 4; ++nf) {
    int cl = n0 + wn * 64 + nf * 16 + (lane & 15);
    float bsv = bias[cl];
#pragma unroll
    for (int mf = 0; mf < 4; ++mf) {
      int r0 = m0 + wm * 64 + mf * 16 + (lane >> 4) * 4;
#pragma unroll
      for (int reg = 0; reg < 4; ++reg)
        C[(size_t)(r0 + reg) * N + cl] = f2bf(acc[mf][nf][reg] + bsv);
    }
  }
}

// ---------------------------------------------------------------------------
// Fused attention for one (chunk-batch bc, head, 64-row q-block).
__global__ __launch_bounds__(256) void attn(const u16* __restrict__ qkv,
                                            u16* __restrict__ o_out, int F) {
  __shared__ u16 q_lds[64 * 136];   // [64][128+8]
  __shared__ u16 k_lds[64 * 136];
  __shared__ u16 vT[128 * 72];      // [128 d][64+8 kpos]
  __shared__ u16 p_lds[4 * 16 * 72];// per-wave [16 qrow][64+8 kpos]

  const int tid  = threadIdx.x;
  const int lane = tid & 63;
  const int w    = tid >> 6;
  const int bc = blockIdx.z, head = blockIdx.y, qb = blockIdx.x;
  const size_t rowbase = (size_t)bc * F * 3072;
  const float scale = 0.08838834764831845f;   // 1/sqrt(128)

  {
    const u16* qsrc = qkv + rowbase + (size_t)(qb * 64) * 3072 + head * 128;
    for (int it = tid; it < 1024; it += 256) {
      int r = it >> 4, s = it & 15;
      bf16x8 v = *(const bf16x8*)(qsrc + (size_t)r * 3072 + s * 8);
      bf16x8 o;
#pragma unroll
      for (int j = 0; j < 8; ++j) o[j] = (short)f2bf(bf2f((u16)v[j]) * scale);
      *(bf16x8*)(q_lds + r * 136 + s * 8) = o;
    }
  }

  f32x4 o_acc[8] = {};
  float m_run = -INFINITY, l_run = 0.f;
  const int qr = lane & 15;   // this lane's qrow (softmax state owner)
  const int g4 = lane >> 4;

  const int nkb = F >> 6;
  for (int kb = 0; kb < nkb; ++kb) {
    __syncthreads();
    const u16* ksrc = qkv + rowbase + (size_t)(kb * 64) * 3072 + 1024 + head * 128;
    const u16* vsrc = qkv + rowbase + (size_t)(kb * 64) * 3072 + 2048 + head * 128;
    for (int it = tid; it < 1024; it += 256) {
      int r = it >> 4, s = it & 15;
      *(bf16x8*)(k_lds + r * 136 + s * 8) = *(const bf16x8*)(ksrc + (size_t)r * 3072 + s * 8);
      bf16x8 v = *(const bf16x8*)(vsrc + (size_t)r * 3072 + s * 8);
      int d0 = s * 8;
#pragma unroll
      for (int j = 0; j < 8; ++j) vT[(d0 + j) * 72 + r] = (u16)v[j];
    }
    __syncthreads();

    // S^T (64 kpos x 16 qrows): A = k rows, B = q^T
    f32x4 sa[4] = {};
#pragma unroll
    for (int kk = 0; kk < 4; ++kk) {
      bf16x8 bq = *(const bf16x8*)(q_lds + (w * 16 + qr) * 136 + kk * 32 + 8 * g4);
#pragma unroll
      for (int f = 0; f < 4; ++f) {
        bf16x8 ak = *(const bf16x8*)(k_lds + (f * 16 + qr) * 136 + kk * 32 + 8 * g4);
        sa[f] = __builtin_amdgcn_mfma_f32_16x16x32_bf16(ak, bq, sa[f], 0, 0, 0);
      }
    }

    float tmax = -INFINITY;
#pragma unroll
    for (int f = 0; f < 4; ++f)
#pragma unroll
      for (int rr = 0; rr < 4; ++rr) tmax = fmaxf(tmax, sa[f][rr]);
    tmax = fmaxf(tmax, __shfl_xor(tmax, 16));
    tmax = fmaxf(tmax, __shfl_xor(tmax, 32));
    float mnew  = fmaxf(m_run, tmax);
    float alpha = __expf(m_run - mnew);
    float psum  = 0.f;
#pragma unroll
    for (int f = 0; f < 4; ++f) {
      u16 pp[4];
#pragma unroll
      for (int rr = 0; rr < 4; ++rr) {
        float p = __expf(sa[f][rr] - mnew);
        psum += p;
        pp[rr] = f2bf(p);
      }
      uint2 u;
      u.x = (u32)pp[0] | ((u32)pp[1] << 16);
      u.y = (u32)pp[2] | ((u32)pp[3] << 16);
      *(uint2*)(p_lds + w * 1152 + qr * 72 + f * 16 + g4 * 4) = u;
    }
    psum += __shfl_xor(psum, 16);
    psum += __shfl_xor(psum, 32);
    l_run = l_run * alpha + psum;
    m_run = mnew;

#pragma unroll
    for (int rr = 0; rr < 4; ++rr) {
      float ar = __shfl(alpha, g4 * 4 + rr);
#pragma unroll
      for (int g = 0; g < 8; ++g) o_acc[g][rr] *= ar;
    }

#pragma unroll
    for (int kk2 = 0; kk2 < 2; ++kk2) {
      bf16x8 pa = *(const bf16x8*)(p_lds + w * 1152 + qr * 72 + kk2 * 32 + 8 * g4);
#pragma unroll
      for (int g = 0; g < 8; ++g) {
        bf16x8 vb = *(const bf16x8*)(vT + (g * 16 + qr) * 72 + kk2 * 32 + 8 * g4);
        o_acc[g] = __builtin_amdgcn_mfma_f32_16x16x32_bf16(pa, vb, o_acc[g], 0, 0, 0);
      }
    }
  }

  float linv = 1.f / l_run;
#pragma unroll
  for (int rr = 0; rr < 4; ++rr) {
    float lr = __shfl(linv, g4 * 4 + rr);
    size_t row = (size_t)bc * F + qb * 64 + w * 16 + g4 * 4 + rr;
#pragma unroll
    for (int g = 0; g < 8; ++g)
      o_out[row * 1024 + head * 128 + g * 16 + qr] = f2bf(o_acc[g][rr] * lr);
  }
}

// ---------------------------------------------------------------------------
__global__ __launch_bounds__(256) void ln_stats(const u16* __restrict__ proj,
                                                float2* __restrict__ stats) {
  int row  = blockIdx.x * 4 + (threadIdx.x >> 6);
  int lane = threadIdx.x & 63;
  const u16* p = proj + (size_t)row * 1024;
  float s = 0.f, s2 = 0.f;
#pragma unroll
  for (int i = 0; i < 2; ++i) {
    bf16x8 v = *(const bf16x8*)(p + (lane + i * 64) * 8);
#pragma unroll
    for (int j = 0; j < 8; ++j) { float f = bf2f((u16)v[j]); s += f; s2 += f * f; }
  }
#pragma unroll
  for (int m = 1; m < 64; m <<= 1) { s += __shfl_xor(s, m); s2 += __shfl_xor(s2, m); }
  if (lane == 0) {
    float mu  = s * (1.f / 1024.f);
    float var = s2 * (1.f / 1024.f) - mu * mu;
    stats[row] = make_float2(mu, rsqrtf(var + 1e-5f));
  }
}

__global__ __launch_bounds__(256) void ln_accum(const u16* __restrict__ proj,
                                                const float2* __restrict__ stats,
                                                const float* __restrict__ g,
                                                const float* __restrict__ beta,
                                                float* __restrict__ dp, int F, int b0) {
  int d  = blockIdx.x * 256 + threadIdx.x;
  int bc = blockIdx.z;
  int f0 = blockIdx.y * 64;
  const u16* base = proj + ((size_t)(bc * F + f0)) * 1024 + d;
  const float2* st = stats + bc * F + f0;
  float acc = 0.f;
  for (int f = 0; f < 64; ++f) {
    float2 s = st[f];
    acc += (bf2f(base[(size_t)f * 1024]) - s.x) * s.y;
  }
  acc = acc * g[d] + 64.f * beta[d];
  atomicAdd(&dp[(size_t)(b0 + bc) * 1024 + d], acc);
}

__global__ __launch_bounds__(256) void cosine_sig(const float* __restrict__ dp,
                                                  const float* __restrict__ tp,
                                                  float* __restrict__ out) {
  __shared__ float red[3][4];
  int b = blockIdx.x;
  int tid = threadIdx.x, lane = tid & 63, w = tid >> 6;
  float dot = 0.f, n1 = 0.f, n2 = 0.f;
  for (int i = tid; i < 1024; i += 256) {
    float a = dp[(size_t)b * 1024 + i], c = tp[(size_t)b * 1024 + i];
    dot += a * c; n1 += a * a; n2 += c * c;
  }
#pragma unroll
  for (int m = 1; m < 64; m <<= 1) {
    dot += __shfl_xor(dot, m); n1 += __shfl_xor(n1, m); n2 += __shfl_xor(n2, m);
  }
  if (lane == 0) { red[0][w] = dot; red[1][w] = n1; red[2][w] = n2; }
  __syncthreads();
  if (tid == 0) {
    dot = red[0][0] + red[0][1] + red[0][2] + red[0][3];
    n1  = red[1][0] + red[1][1] + red[1][2] + red[1][3];
    n2  = red[2][0] + red[2][1] + red[2][2] + red[2][3];
    float denom = fmaxf(sqrtf(n1) * sqrtf(n2), 1e-8f);
    out[b] = 1.f / (1.f + __expf(-dot / denom));
  }
}

// ---------------------------------------------------------------------------
extern "C" void kernel_launch(void* const* d_in, const int* in_sizes, int n_in,
                              void* d_out, int out_size, void* d_ws, size_t ws_size,
                              hipStream_t stream) {
  const float* drug   = (const float*)d_in[0];
  const float* target = (const float*)d_in[1];

  char* p = (char*)d_ws;
  auto alloc = [&](size_t bytes) -> char* {
    char* r = p; p += (bytes + 255) & ~(size_t)255; return r;
  };

  u16* w_in_d  = (u16*)alloc((size_t)3072 * 1024 * 2);
  u16* w_out_d = (u16*)alloc((size_t)1024 * 1024 * 2);
  u16* w_in_t  = (u16*)alloc((size_t)3072 * 1024 * 2);
  u16* w_out_t = (u16*)alloc((size_t)1024 * 1024 * 2);
  float* dp    = (float*)alloc((size_t)2 * 128 * 1024 * 4);
  float* tp    = dp + 128 * 1024;

  size_t fixed = (size_t)(p - (char*)d_ws);
  size_t per = (size_t)256 * 1024 * 2 * 3
             + (size_t)256 * 3072 * 2
             + (size_t)256 * 8 + 2048;
  int Bc = 8;
  if      (fixed + 128 * per <= ws_size) Bc = 128;
  else if (fixed +  64 * per <= ws_size) Bc = 64;
  else if (fixed +  32 * per <= ws_size) Bc = 32;
  else if (fixed +  16 * per <= ws_size) Bc = 16;

  u16* hbuf    = (u16*)alloc((size_t)Bc * 256 * 1024 * 2);
  u16* qkvbuf  = (u16*)alloc((size_t)Bc * 256 * 3072 * 2);
  u16* obuf    = (u16*)alloc((size_t)Bc * 256 * 1024 * 2);
  u16* projbuf = (u16*)alloc((size_t)Bc * 256 * 1024 * 2);
  float2* statsb = (float2*)alloc((size_t)Bc * 256 * 8);

  cvt_bf16<<<1536, 256, 0, stream>>>((const float*)d_in[4],  w_in_d,  3072 * 128);
  cvt_bf16<<<512,  256, 0, stream>>>((const float*)d_in[6],  w_out_d, 1024 * 128);
  cvt_bf16<<<1536, 256, 0, stream>>>((const float*)d_in[12], w_in_t,  3072 * 128);
  cvt_bf16<<<512,  256, 0, stream>>>((const float*)d_in[14], w_out_t, 1024 * 128);
  hipMemsetAsync(dp, 0, (size_t)2 * 128 * 1024 * 4, stream);

  for (int br = 0; br < 2; ++br) {
    const int F = br ? 128 : 256, logF = br ? 7 : 8, xstride = br ? 1024 : 2048;
    const float* x    = br ? target : drug;
    const float* W    = (const float*)d_in[br ? 10 : 2];
    const float* Wb   = (const float*)d_in[br ? 11 : 3];
    u16*         win  = br ? w_in_t : w_in_d;
    const float* inb  = (const float*)d_in[br ? 13 : 5];
    u16*         wout = br ? w_out_t : w_out_d;
    const float* outb = (const float*)d_in[br ? 15 : 7];
    const float* gg   = (const float*)d_in[br ? 16 : 8];
    const float* bb   = (const float*)d_in[br ? 17 : 9];
    float*       accp = br ? tp : dp;

    for (int b0 = 0; b0 < 128; b0 += Bc) {
      const int Mr = Bc * F;
      hgen<<<Mr * 128 / 256, 256, 0, stream>>>(x, W, Wb, hbuf, F, logF, b0, xstride, Mr * 128);
      gemm256<<<dim3(3072 / 128, Mr / 256), 512, 0, stream>>>(hbuf, win, inb, qkvbuf, Mr, 3072, 1024);
      attn<<<dim3(F / 64, 8, Bc), 256, 0, stream>>>(qkvbuf, obuf, F);
      gemm256<<<dim3(1024 / 128, Mr / 256), 512, 0, stream>>>(obuf, wout, outb, projbuf, Mr, 1024, 1024);
      ln_stats<<<Mr / 4, 256, 0, stream>>>(projbuf, statsb);
      ln_accum<<<dim3(4, F / 64, Bc), 256, 0, stream>>>(projbuf, statsb, gg, bb, accp, F, b0);
    }
  }
  cosine_sig<<<128, 256, 0, stream>>>(dp, tp, (float*)d_out);
}

// Round 4
// 845.062 us; speedup vs baseline: 1.0368x; 1.0117x over previous
//
#include <hip/hip_runtime.h>

typedef unsigned short u16;
typedef unsigned int   u32;

using bf16x8 = __attribute__((ext_vector_type(8))) short;  // 8 bf16 in 4 VGPRs
using f32x4  = __attribute__((ext_vector_type(4))) float;

__device__ __forceinline__ float bf2f(u16 h) {
  u32 u = ((u32)h) << 16;
  return __builtin_bit_cast(float, u);
}
__device__ __forceinline__ u16 f2bf(float f) {   // round-to-nearest-even
  u32 u = __builtin_bit_cast(u32, f);
  u += 0x7fffu + ((u >> 16) & 1u);
  return (u16)(u >> 16);
}

__device__ __forceinline__ void gload16(const u16* src, u16* ldsdst) {
  __builtin_amdgcn_global_load_lds(
      (const __attribute__((address_space(1))) void*)src,
      (__attribute__((address_space(3))) void*)ldsdst, 16, 0, 0);
}

// ---------------------------------------------------------------------------
__global__ __launch_bounds__(256) void cvt_bf16(const float* __restrict__ in,
                                                u16* __restrict__ out, int n8) {
  int i = blockIdx.x * 256 + threadIdx.x;
  if (i >= n8) return;
  const float* p = in + (size_t)i * 8;
  bf16x8 o;
#pragma unroll
  for (int j = 0; j < 8; ++j) o[j] = (short)f2bf(p[j]);
  *(bf16x8*)(out + (size_t)i * 8) = o;
}

// ---------------------------------------------------------------------------
__global__ __launch_bounds__(256) void hgen(const float* __restrict__ x,
                                            const float* __restrict__ W,
                                            const float* __restrict__ bias,
                                            u16* __restrict__ h, int F, int logF,
                                            int b0, int xstride, int total8) {
  int idx = blockIdx.x * 256 + threadIdx.x;
  if (idx >= total8) return;
  int d0 = (idx & 127) << 3;
  int m  = idx >> 7;
  int f  = m & (F - 1);
  int b  = b0 + (m >> logF);
  float xv = x[(size_t)b * xstride + f];
  const float* wp = W + (size_t)f * 1024 + d0;
  const float* bp = bias + (size_t)f * 1024 + d0;
  bf16x8 o;
#pragma unroll
  for (int j = 0; j < 8; ++j) o[j] = (short)f2bf(fmaxf(xv * wp[j] + bp[j], 0.f));
  *(bf16x8*)(h + (size_t)m * 1024 + d0) = o;
}

// ---------------------------------------------------------------------------
// C(MxN, bf16) = A(MxK, bf16) * B^T (B stored NxK) + bias(N, f32)
// 256x256 tile, BK=64, 8 waves (2M x 4N), per-wave out 128x64.
// m201-style 8-phase schedule: per phase {ds_read subtile || stage 1 half-tile
// (2x gload16) ; barrier ; lgkmcnt(0) ; setprio(1) ; 16 MFMA ; setprio(0) ;
// [vmcnt(6) at phases 4,8] ; barrier}.  2 LDS dbufs, 2 K-tiles per iter.
// Stage-slot ledger (verified): iter i, T=2i:
//   p1: buf1.Ar1[T+1]  p2: buf0.Ar0[T+2]  p3: buf0.Bc0[T+2]  p4: buf0.Bc1[T+2]
//   p5: buf0.Ar1[T+2]  p6: buf1.Ar0[T+3]  p7: buf1.Bc0[T+3]  p8: buf1.Bc1[T+3]
// vmcnt(6)@p4 retires {p6,p7,p8 prev, p1 cur} = tile T+1; @p8 retires
// {p2..p5} = tile T+2.  Last iter: vmcnt(0)@p4 (tail under-retires otherwise).
// Requires M%256==0, N%256==0, K%128==0.
__global__ __launch_bounds__(512, 2) void gemm8p(const u16* __restrict__ A,
                                                 const u16* __restrict__ B,
                                                 const float* __restrict__ bias,
                                                 u16* __restrict__ C,
                                                 int M, int N, int K) {
  __shared__ u16 sA[2][16384];   // [buf][256 rows x 64 k]  (chunk = 8 rows = 1KB)
  __shared__ u16 sB[2][16384];
  const int tid  = threadIdx.x;
  const int lane = tid & 63;
  const int w    = tid >> 6;
  const int wm   = w >> 2;        // 0..1 : 128-row group
  const int wn   = w & 3;         // 0..3 : 64-col group

  // bijective XCD swizzle (m204)
  const int nwg = gridDim.x * gridDim.y;
  const int wg  = blockIdx.y * gridDim.x + blockIdx.x;
  const int q = nwg >> 3, r = nwg & 7, xcd = wg & 7, loc = wg >> 3;
  const int swz = (xcd < r ? xcd * (q + 1) : r * (q + 1) + (xcd - r) * q) + loc;
  const int n0 = (swz % gridDim.x) * 256;
  const int m0 = (swz / gridDim.x) * 256;

  f32x4 acc[8][4] = {};

  const int r_in  = lane >> 3;             // row within 8-row chunk
  const int s_log = (lane & 7) ^ r_in;     // pre-swizzled 16B slot to fetch

  // stage A half (half 0: rows 0-63 & 128-191; half 1: rows 64-127 & 192-255)
  auto stA = [&](int b, int half, int kt) {
    int c  = half * 8 + w;
    int k0 = kt << 6;
    gload16(A + (size_t)(m0 + c * 8 + r_in) * K + k0 + s_log * 8, &sA[b][c * 512]);
    gload16(A + (size_t)(m0 + (c + 16) * 8 + r_in) * K + k0 + s_log * 8, &sA[b][(c + 16) * 512]);
  };
  // stage B quarter-set (half 0: rows {0-31,64-95,128-159,192-223}; half 1: +32)
  auto stB = [&](int b, int half, int kt) {
    int c  = half * 4 + (w & 3) + (w >> 2) * 8;
    int k0 = kt << 6;
    gload16(B + (size_t)(n0 + c * 8 + r_in) * K + k0 + s_log * 8, &sB[b][c * 512]);
    gload16(B + (size_t)(n0 + (c + 16) * 8 + r_in) * K + k0 + s_log * 8, &sB[b][(c + 16) * 512]);
  };

  bf16x8 af[4][2], bg0[2][2], bg1[2][2];

#define RD_A(b, rq)                                                              \
  _Pragma("unroll") for (int mf = 0; mf < 4; ++mf) {                             \
    int ra = wm * 128 + (rq) * 64 + mf * 16 + (lane & 15);                       \
    _Pragma("unroll") for (int kk = 0; kk < 2; ++kk) {                           \
      int sl = kk * 4 + (lane >> 4);                                             \
      af[mf][kk] = *(const bf16x8*)(&sA[b][ra * 64 + ((sl ^ (ra & 7)) * 8)]);    \
    }                                                                            \
  }
#define RD_B(b, cq, BG)                                                          \
  _Pragma("unroll") for (int nf = 0; nf < 2; ++nf) {                             \
    int rb = wn * 64 + (cq) * 32 + nf * 16 + (lane & 15);                        \
    _Pragma("unroll") for (int kk = 0; kk < 2; ++kk) {                           \
      int sl = kk * 4 + (lane >> 4);                                             \
      BG[nf][kk] = *(const bf16x8*)(&sB[b][rb * 64 + ((sl ^ (rb & 7)) * 8)]);    \
    }                                                                            \
  }
#define MMA_Q(rq, cq, BG)                                                        \
  _Pragma("unroll") for (int mf = 0; mf < 4; ++mf)                               \
  _Pragma("unroll") for (int nf = 0; nf < 2; ++nf)                               \
  _Pragma("unroll") for (int kk = 0; kk < 2; ++kk)                               \
    acc[(rq)*4+mf][(cq)*2+nf] = __builtin_amdgcn_mfma_f32_16x16x32_bf16(         \
        af[mf][kk], BG[nf][kk], acc[(rq)*4+mf][(cq)*2+nf], 0, 0, 0);
#define PH_SYNC()                                            \
  __builtin_amdgcn_s_barrier();                              \
  asm volatile("s_waitcnt lgkmcnt(0)" ::: "memory");         \
  __builtin_amdgcn_sched_barrier(0);                         \
  __builtin_amdgcn_s_setprio(1)
#define PH_END()                                             \
  __builtin_amdgcn_s_setprio(0);                             \
  __builtin_amdgcn_s_barrier()
#define PH_END_VM6()                                         \
  __builtin_amdgcn_s_setprio(0);                             \
  asm volatile("s_waitcnt vmcnt(6)" ::: "memory");           \
  __builtin_amdgcn_s_barrier()
#define PH_END_VM0()                                         \
  __builtin_amdgcn_s_setprio(0);                             \
  asm volatile("s_waitcnt vmcnt(0)" ::: "memory");           \
  __builtin_amdgcn_s_barrier()

  const int NT = K >> 6;
  // prologue: tile0 -> buf0 (8 loads), tile1 Ar0/Bc0/Bc1 -> buf1 (6 loads)
  stA(0, 0, 0); stB(0, 0, 0); stB(0, 1, 0); stA(0, 1, 0);
  stA(1, 0, 1); stB(1, 0, 1); stB(1, 1, 1);
  asm volatile("s_waitcnt vmcnt(6)" ::: "memory");
  __builtin_amdgcn_s_barrier();

  const int niter = NT >> 1;
  for (int it = 0; it < niter; ++it) {
    const int t = it * 2;
    const bool nl = (it != niter - 1);   // not last

    // p1: Q00 of tile t (buf0)
    RD_A(0, 0); RD_B(0, 0, bg0);
    stA(1, 1, t + 1);
    PH_SYNC(); MMA_Q(0, 0, bg0); PH_END();
    // p2: Q01
    RD_B(0, 1, bg1);
    if (nl) stA(0, 0, t + 2);
    PH_SYNC(); MMA_Q(0, 1, bg1); PH_END();
    // p3: Q10
    RD_A(0, 1);
    if (nl) stB(0, 0, t + 2);
    PH_SYNC(); MMA_Q(1, 0, bg0); PH_END();
    // p4: Q11  (+vmcnt)
    if (nl) stB(0, 1, t + 2);
    PH_SYNC(); MMA_Q(1, 1, bg1);
    if (nl) { PH_END_VM6(); } else { PH_END_VM0(); }

    // p5: Q00 of tile t+1 (buf1)
    RD_A(1, 0); RD_B(1, 0, bg0);
    if (nl) stA(0, 1, t + 2);
    PH_SYNC(); MMA_Q(0, 0, bg0); PH_END();
    // p6: Q01
    RD_B(1, 1, bg1);
    if (nl) stA(1, 0, t + 3);
    PH_SYNC(); MMA_Q(0, 1, bg1); PH_END();
    // p7: Q10
    RD_A(1, 1);
    if (nl) stB(1, 0, t + 3);
    PH_SYNC(); MMA_Q(1, 0, bg0); PH_END();
    // p8: Q11  (+vmcnt)
    if (nl) stB(1, 1, t + 3);
    PH_SYNC(); MMA_Q(1, 1, bg1); PH_END_VM6();
  }

  // epilogue: D layout col = lane&15, row = (lane>>4)*4 + reg
#pragma unroll
  for (int i8 = 0; i8 < 8; ++i8) {
    int r0 = m0 + wm * 128 + i8 * 16 + (lane >> 4) * 4;
#pragma unroll
    for (int j4 = 0; j4 < 4; ++j4) {
      int cl = n0 + wn * 64 + j4 * 16 + (lane & 15);
      float bsv = bias[cl];
#pragma unroll
      for (int reg = 0; reg < 4; ++reg)
        C[(size_t)(r0 + reg) * N + cl] = f2bf(acc[i8][j4][reg] + bsv);
    }
  }
#undef RD_A
#undef RD_B
#undef MMA_Q
#undef PH_SYNC
#undef PH_END
#undef PH_END_VM6
#undef PH_END_VM0
}

// ---------------------------------------------------------------------------
// Fused attention for one (chunk-batch bc, head, 64-row q-block).
__global__ __launch_bounds__(256) void attn(const u16* __restrict__ qkv,
                                            u16* __restrict__ o_out, int F) {
  __shared__ u16 q_lds[64 * 136];   // [64][128+8]
  __shared__ u16 k_lds[64 * 136];
  __shared__ u16 vT[128 * 72];      // [128 d][64+8 kpos]
  __shared__ u16 p_lds[4 * 16 * 72];// per-wave [16 qrow][64+8 kpos]

  const int tid  = threadIdx.x;
  const int lane = tid & 63;
  const int w    = tid >> 6;
  const int bc = blockIdx.z, head = blockIdx.y, qb = blockIdx.x;
  const size_t rowbase = (size_t)bc * F * 3072;
  const float scale = 0.08838834764831845f;   // 1/sqrt(128)

  {
    const u16* qsrc = qkv + rowbase + (size_t)(qb * 64) * 3072 + head * 128;
    for (int it = tid; it < 1024; it += 256) {
      int r = it >> 4, s = it & 15;
      bf16x8 v = *(const bf16x8*)(qsrc + (size_t)r * 3072 + s * 8);
      bf16x8 o;
#pragma unroll
      for (int j = 0; j < 8; ++j) o[j] = (short)f2bf(bf2f((u16)v[j]) * scale);
      *(bf16x8*)(q_lds + r * 136 + s * 8) = o;
    }
  }

  f32x4 o_acc[8] = {};
  float m_run = -INFINITY, l_run = 0.f;
  const int qr = lane & 15;
  const int g4 = lane >> 4;

  const int nkb = F >> 6;
  for (int kb = 0; kb < nkb; ++kb) {
    __syncthreads();
    const u16* ksrc = qkv + rowbase + (size_t)(kb * 64) * 3072 + 1024 + head * 128;
    const u16* vsrc = qkv + rowbase + (size_t)(kb * 64) * 3072 + 2048 + head * 128;
    for (int it = tid; it < 1024; it += 256) {
      int r = it >> 4, s = it & 15;
      *(bf16x8*)(k_lds + r * 136 + s * 8) = *(const bf16x8*)(ksrc + (size_t)r * 3072 + s * 8);
      bf16x8 v = *(const bf16x8*)(vsrc + (size_t)r * 3072 + s * 8);
      int d0 = s * 8;
#pragma unroll
      for (int j = 0; j < 8; ++j) vT[(d0 + j) * 72 + r] = (u16)v[j];
    }
    __syncthreads();

    f32x4 sa[4] = {};
#pragma unroll
    for (int kk = 0; kk < 4; ++kk) {
      bf16x8 bq = *(const bf16x8*)(q_lds + (w * 16 + qr) * 136 + kk * 32 + 8 * g4);
#pragma unroll
      for (int f = 0; f < 4; ++f) {
        bf16x8 ak = *(const bf16x8*)(k_lds + (f * 16 + qr) * 136 + kk * 32 + 8 * g4);
        sa[f] = __builtin_amdgcn_mfma_f32_16x16x32_bf16(ak, bq, sa[f], 0, 0, 0);
      }
    }

    float tmax = -INFINITY;
#pragma unroll
    for (int f = 0; f < 4; ++f)
#pragma unroll
      for (int rr = 0; rr < 4; ++rr) tmax = fmaxf(tmax, sa[f][rr]);
    tmax = fmaxf(tmax, __shfl_xor(tmax, 16));
    tmax = fmaxf(tmax, __shfl_xor(tmax, 32));
    float mnew  = fmaxf(m_run, tmax);
    float alpha = __expf(m_run - mnew);
    float psum  = 0.f;
#pragma unroll
    for (int f = 0; f < 4; ++f) {
      u16 pp[4];
#pragma unroll
      for (int rr = 0; rr < 4; ++rr) {
        float p = __expf(sa[f][rr] - mnew);
        psum += p;
        pp[rr] = f2bf(p);
      }
      uint2 u;
      u.x = (u32)pp[0] | ((u32)pp[1] << 16);
      u.y = (u32)pp[2] | ((u32)pp[3] << 16);
      *(uint2*)(p_lds + w * 1152 + qr * 72 + f * 16 + g4 * 4) = u;
    }
    psum += __shfl_xor(psum, 16);
    psum += __shfl_xor(psum, 32);
    l_run = l_run * alpha + psum;
    m_run = mnew;

#pragma unroll
    for (int rr = 0; rr < 4; ++rr) {
      float ar = __shfl(alpha, g4 * 4 + rr);
#pragma unroll
      for (int g = 0; g < 8; ++g) o_acc[g][rr] *= ar;
    }

#pragma unroll
    for (int kk2 = 0; kk2 < 2; ++kk2) {
      bf16x8 pa = *(const bf16x8*)(p_lds + w * 1152 + qr * 72 + kk2 * 32 + 8 * g4);
#pragma unroll
      for (int g = 0; g < 8; ++g) {
        bf16x8 vb = *(const bf16x8*)(vT + (g * 16 + qr) * 72 + kk2 * 32 + 8 * g4);
        o_acc[g] = __builtin_amdgcn_mfma_f32_16x16x32_bf16(pa, vb, o_acc[g], 0, 0, 0);
      }
    }
  }

  float linv = 1.f / l_run;
#pragma unroll
  for (int rr = 0; rr < 4; ++rr) {
    float lr = __shfl(linv, g4 * 4 + rr);
    size_t row = (size_t)bc * F + qb * 64 + w * 16 + g4 * 4 + rr;
#pragma unroll
    for (int g = 0; g < 8; ++g)
      o_out[row * 1024 + head * 128 + g * 16 + qr] = f2bf(o_acc[g][rr] * lr);
  }
}

// ---------------------------------------------------------------------------
__global__ __launch_bounds__(256) void ln_stats(const u16* __restrict__ proj,
                                                float2* __restrict__ stats) {
  int row  = blockIdx.x * 4 + (threadIdx.x >> 6);
  int lane = threadIdx.x & 63;
  const u16* p = proj + (size_t)row * 1024;
  float s = 0.f, s2 = 0.f;
#pragma unroll
  for (int i = 0; i < 2; ++i) {
    bf16x8 v = *(const bf16x8*)(p + (lane + i * 64) * 8);
#pragma unroll
    for (int j = 0; j < 8; ++j) { float f = bf2f((u16)v[j]); s += f; s2 += f * f; }
  }
#pragma unroll
  for (int m = 1; m < 64; m <<= 1) { s += __shfl_xor(s, m); s2 += __shfl_xor(s2, m); }
  if (lane == 0) {
    float mu  = s * (1.f / 1024.f);
    float var = s2 * (1.f / 1024.f) - mu * mu;
    stats[row] = make_float2(mu, rsqrtf(var + 1e-5f));
  }
}

__global__ __launch_bounds__(256) void ln_accum(const u16* __restrict__ proj,
                                                const float2* __restrict__ stats,
                                                const float* __restrict__ g,
                                                const float* __restrict__ beta,
                                                float* __restrict__ dp, int F, int b0) {
  int d  = blockIdx.x * 256 + threadIdx.x;
  int bc = blockIdx.z;
  int f0 = blockIdx.y * 64;
  const u16* base = proj + ((size_t)(bc * F + f0)) * 1024 + d;
  const float2* st = stats + bc * F + f0;
  float acc = 0.f;
  for (int f = 0; f < 64; ++f) {
    float2 s = st[f];
    acc += (bf2f(base[(size_t)f * 1024]) - s.x) * s.y;
  }
  acc = acc * g[d] + 64.f * beta[d];
  atomicAdd(&dp[(size_t)(b0 + bc) * 1024 + d], acc);
}

__global__ __launch_bounds__(256) void cosine_sig(const float* __restrict__ dp,
                                                  const float* __restrict__ tp,
                                                  float* __restrict__ out) {
  __shared__ float red[3][4];
  int b = blockIdx.x;
  int tid = threadIdx.x, lane = tid & 63, w = tid >> 6;
  float dot = 0.f, n1 = 0.f, n2 = 0.f;
  for (int i = tid; i < 1024; i += 256) {
    float a = dp[(size_t)b * 1024 + i], c = tp[(size_t)b * 1024 + i];
    dot += a * c; n1 += a * a; n2 += c * c;
  }
#pragma unroll
  for (int m = 1; m < 64; m <<= 1) {
    dot += __shfl_xor(dot, m); n1 += __shfl_xor(n1, m); n2 += __shfl_xor(n2, m);
  }
  if (lane == 0) { red[0][w] = dot; red[1][w] = n1; red[2][w] = n2; }
  __syncthreads();
  if (tid == 0) {
    dot = red[0][0] + red[0][1] + red[0][2] + red[0][3];
    n1  = red[1][0] + red[1][1] + red[1][2] + red[1][3];
    n2  = red[2][0] + red[2][1] + red[2][2] + red[2][3];
    float denom = fmaxf(sqrtf(n1) * sqrtf(n2), 1e-8f);
    out[b] = 1.f / (1.f + __expf(-dot / denom));
  }
}

// ---------------------------------------------------------------------------
extern "C" void kernel_launch(void* const* d_in, const int* in_sizes, int n_in,
                              void* d_out, int out_size, void* d_ws, size_t ws_size,
                              hipStream_t stream) {
  const float* drug   = (const float*)d_in[0];
  const float* target = (const float*)d_in[1];

  char* p = (char*)d_ws;
  auto alloc = [&](size_t bytes) -> char* {
    char* r = p; p += (bytes + 255) & ~(size_t)255; return r;
  };

  u16* w_in_d  = (u16*)alloc((size_t)3072 * 1024 * 2);
  u16* w_out_d = (u16*)alloc((size_t)1024 * 1024 * 2);
  u16* w_in_t  = (u16*)alloc((size_t)3072 * 1024 * 2);
  u16* w_out_t = (u16*)alloc((size_t)1024 * 1024 * 2);
  float* dp    = (float*)alloc((size_t)2 * 128 * 1024 * 4);
  float* tp    = dp + 128 * 1024;

  size_t fixed = (size_t)(p - (char*)d_ws);
  size_t per = (size_t)256 * 1024 * 2 * 3
             + (size_t)256 * 3072 * 2
             + (size_t)256 * 8 + 2048;
  int Bc = 8;
  if      (fixed + 128 * per <= ws_size) Bc = 128;
  else if (fixed +  64 * per <= ws_size) Bc = 64;
  else if (fixed +  32 * per <= ws_size) Bc = 32;
  else if (fixed +  16 * per <= ws_size) Bc = 16;

  u16* hbuf    = (u16*)alloc((size_t)Bc * 256 * 1024 * 2);
  u16* qkvbuf  = (u16*)alloc((size_t)Bc * 256 * 3072 * 2);
  u16* obuf    = (u16*)alloc((size_t)Bc * 256 * 1024 * 2);
  u16* projbuf = (u16*)alloc((size_t)Bc * 256 * 1024 * 2);
  float2* statsb = (float2*)alloc((size_t)Bc * 256 * 8);

  cvt_bf16<<<1536, 256, 0, stream>>>((const float*)d_in[4],  w_in_d,  3072 * 128);
  cvt_bf16<<<512,  256, 0, stream>>>((const float*)d_in[6],  w_out_d, 1024 * 128);
  cvt_bf16<<<1536, 256, 0, stream>>>((const float*)d_in[12], w_in_t,  3072 * 128);
  cvt_bf16<<<512,  256, 0, stream>>>((const float*)d_in[14], w_out_t, 1024 * 128);
  hipMemsetAsync(dp, 0, (size_t)2 * 128 * 1024 * 4, stream);

  for (int br = 0; br < 2; ++br) {
    const int F = br ? 128 : 256, logF = br ? 7 : 8, xstride = br ? 1024 : 2048;
    const float* x    = br ? target : drug;
    const float* W    = (const float*)d_in[br ? 10 : 2];
    const float* Wb   = (const float*)d_in[br ? 11 : 3];
    u16*         win  = br ? w_in_t : w_in_d;
    const float* inb  = (const float*)d_in[br ? 13 : 5];
    u16*         wout = br ? w_out_t : w_out_d;
    const float* outb = (const float*)d_in[br ? 15 : 7];
    const float* gg   = (const float*)d_in[br ? 16 : 8];
    const float* bb   = (const float*)d_in[br ? 17 : 9];
    float*       accp = br ? tp : dp;

    for (int b0 = 0; b0 < 128; b0 += Bc) {
      const int Mr = Bc * F;
      hgen<<<Mr * 128 / 256, 256, 0, stream>>>(x, W, Wb, hbuf, F, logF, b0, xstride, Mr * 128);
      gemm8p<<<dim3(3072 / 256, Mr / 256), 512, 0, stream>>>(hbuf, win, inb, qkvbuf, Mr, 3072, 1024);
      attn<<<dim3(F / 64, 8, Bc), 256, 0, stream>>>(qkvbuf, obuf, F);
      gemm8p<<<dim3(1024 / 256, Mr / 256), 512, 0, stream>>>(obuf, wout, outb, projbuf, Mr, 1024, 1024);
      ln_stats<<<Mr / 4, 256, 0, stream>>>(projbuf, statsb);
      ln_accum<<<dim3(4, F / 64, Bc), 256, 0, stream>>>(projbuf, statsb, gg, bb, accp, F, b0);
    }
  }
  cosine_sig<<<128, 256, 0, stream>>>(dp, tp, (float*)d_out);
}

// Round 5
// 829.999 us; speedup vs baseline: 1.0557x; 1.0181x over previous
//
#include <hip/hip_runtime.h>

typedef unsigned short u16;
typedef unsigned int   u32;

using bf16x8 = __attribute__((ext_vector_type(8))) short;  // 8 bf16 in 4 VGPRs
using f32x4  = __attribute__((ext_vector_type(4))) float;

__device__ __forceinline__ float bf2f(u16 h) {
  u32 u = ((u32)h) << 16;
  return __builtin_bit_cast(float, u);
}
__device__ __forceinline__ u16 f2bf(float f) {   // round-to-nearest-even
  u32 u = __builtin_bit_cast(u32, f);
  u += 0x7fffu + ((u >> 16) & 1u);
  return (u16)(u >> 16);
}

__device__ __forceinline__ void gload16(const u16* src, u16* ldsdst) {
  __builtin_amdgcn_global_load_lds(
      (const __attribute__((address_space(1))) void*)src,
      (__attribute__((address_space(3))) void*)ldsdst, 16, 0, 0);
}

// m204 bijective XCD swizzle
__device__ __forceinline__ int xcd_swz(int wg, int nwg) {
  int q = nwg >> 3, r = nwg & 7, xcd = wg & 7, loc = wg >> 3;
  return (xcd < r ? xcd * (q + 1) : r * (q + 1) + (xcd - r) * q) + loc;
}

// ---------------------------------------------------------------------------
__global__ __launch_bounds__(256) void cvt_bf16(const float* __restrict__ in,
                                                u16* __restrict__ out, int n8) {
  int i = blockIdx.x * 256 + threadIdx.x;
  if (i >= n8) return;
  const float* p = in + (size_t)i * 8;
  bf16x8 o;
#pragma unroll
  for (int j = 0; j < 8; ++j) o[j] = (short)f2bf(p[j]);
  *(bf16x8*)(out + (size_t)i * 8) = o;
}

// ---------------------------------------------------------------------------
__global__ __launch_bounds__(256) void hgen(const float* __restrict__ x,
                                            const float* __restrict__ W,
                                            const float* __restrict__ bias,
                                            u16* __restrict__ h, int F, int logF,
                                            int b0, int xstride, int total8) {
  int idx = blockIdx.x * 256 + threadIdx.x;
  if (idx >= total8) return;
  int d0 = (idx & 127) << 3;
  int m  = idx >> 7;
  int f  = m & (F - 1);
  int b  = b0 + (m >> logF);
  float xv = x[(size_t)b * xstride + f];
  const float* wp = W + (size_t)f * 1024 + d0;
  const float* bp = bias + (size_t)f * 1024 + d0;
  bf16x8 o;
#pragma unroll
  for (int j = 0; j < 8; ++j) o[j] = (short)f2bf(fmaxf(xv * wp[j] + bp[j], 0.f));
  *(bf16x8*)(h + (size_t)m * 1024 + d0) = o;
}

// ---------------------------------------------------------------------------
// C(MxN, bf16) = A(MxK, bf16) * B^T (B stored NxK) + bias(N, f32)
// 256x128 tile, BK=32, 8 waves (4M x 2N), per-wave 64x64 out (acc=64 regs).
// Sized for 2 blocks/CU: LDS 48 KB, total regs <=128/wave (launch_bounds 512,4).
// One barrier per K-tile: {stage t+1 -> buf^1 ; ds_read buf ; lgkmcnt(0) ;
// 16 MFMA ; vmcnt(0) ; s_barrier}.  Cross-wave safety: every wave's stage
// loads retire at its own vmcnt(0) BEFORE the barrier, so after the barrier
// all chunks of tile t+1 have landed; reads of buf^1 drained at lgkmcnt(0)
// before the previous barrier, so stage writes never race reads.
// Requires M%256==0, N%128==0, K%32==0.
__global__ __launch_bounds__(512, 4) void gemm_ph(const u16* __restrict__ A,
                                                  const u16* __restrict__ B,
                                                  const float* __restrict__ bias,
                                                  u16* __restrict__ C,
                                                  int M, int N, int K) {
  __shared__ u16 sA[2][256 * 32];   // 2 x 16 KB, chunk = 16 rows x 64 B
  __shared__ u16 sB[2][128 * 32];   // 2 x  8 KB
  const int tid  = threadIdx.x;
  const int lane = tid & 63;
  const int w    = tid >> 6;
  const int wm   = w >> 1;          // 0..3 : 64-row group
  const int wn   = w & 1;           // 0..1 : 64-col group

  const int nwg = gridDim.x * gridDim.y;
  const int wg  = blockIdx.y * gridDim.x + blockIdx.x;
  const int swz = xcd_swz(wg, nwg);
  const int n0 = (swz % gridDim.x) * 128;
  const int m0 = (swz / gridDim.x) * 256;

  f32x4 acc[4][4] = {};

  const int r_in  = lane >> 2;                 // 0..15 row within 16-row chunk
  const int s_src = (lane & 3) ^ (r_in & 3);   // pre-swizzled 16B slot to fetch

  // stage one K-tile: A chunks {w, w+8}, B chunk {w}; 3 gloads/wave
  auto stage = [&](int kt, int b) {
    const int k0 = kt << 5;
    gload16(A + (size_t)(m0 + w * 16 + r_in) * K + k0 + s_src * 8, &sA[b][w * 512]);
    gload16(A + (size_t)(m0 + (w + 8) * 16 + r_in) * K + k0 + s_src * 8, &sA[b][(w + 8) * 512]);
    gload16(B + (size_t)(n0 + w * 16 + r_in) * K + k0 + s_src * 8, &sB[b][w * 512]);
  };

  const int NT = K >> 5;
  stage(0, 0);
  asm volatile("s_waitcnt vmcnt(0)" ::: "memory");
  __builtin_amdgcn_s_barrier();

  int cur = 0;
  for (int t = 0; t < NT; ++t) {
    if (t + 1 < NT) stage(t + 1, cur ^ 1);

    bf16x8 af[4], bg[4];
    const int g = lane >> 4;         // logical 16B k-slot (k = g*8 + j)
#pragma unroll
    for (int mf = 0; mf < 4; ++mf) {
      int ra = wm * 64 + mf * 16 + (lane & 15);
      af[mf] = *(const bf16x8*)(&sA[cur][ra * 32 + ((g ^ (ra & 3)) * 8)]);
    }
#pragma unroll
    for (int nf = 0; nf < 4; ++nf) {
      int rb = wn * 64 + nf * 16 + (lane & 15);
      bg[nf] = *(const bf16x8*)(&sB[cur][rb * 32 + ((g ^ (rb & 3)) * 8)]);
    }
    asm volatile("s_waitcnt lgkmcnt(0)" ::: "memory");
    __builtin_amdgcn_sched_barrier(0);
    __builtin_amdgcn_s_setprio(1);
#pragma unroll
    for (int mf = 0; mf < 4; ++mf)
#pragma unroll
      for (int nf = 0; nf < 4; ++nf)
        acc[mf][nf] = __builtin_amdgcn_mfma_f32_16x16x32_bf16(af[mf], bg[nf], acc[mf][nf], 0, 0, 0);
    __builtin_amdgcn_s_setprio(0);
    asm volatile("s_waitcnt vmcnt(0)" ::: "memory");
    __builtin_amdgcn_s_barrier();
    cur ^= 1;
  }

  // epilogue: D layout col = lane&15, row = (lane>>4)*4 + reg
#pragma unroll
  for (int nf = 0; nf < 4; ++nf) {
    int cl = n0 + wn * 64 + nf * 16 + (lane & 15);
    float bsv = bias[cl];
#pragma unroll
    for (int mf = 0; mf < 4; ++mf) {
      int r0 = m0 + wm * 64 + mf * 16 + (lane >> 4) * 4;
#pragma unroll
      for (int reg = 0; reg < 4; ++reg)
        C[(size_t)(r0 + reg) * N + cl] = f2bf(acc[mf][nf][reg] + bsv);
    }
  }
}

// ---------------------------------------------------------------------------
// Fused attention for one (bc, head, 64-row q-block); 1-D grid + XCD swizzle
// so blocks sharing a KV panel co-locate on one XCD (L2 reuse).
__global__ __launch_bounds__(256) void attn(const u16* __restrict__ qkv,
                                            u16* __restrict__ o_out, int F) {
  __shared__ u16 q_lds[64 * 136];   // [64][128+8]
  __shared__ u16 k_lds[64 * 136];
  __shared__ u16 vT[128 * 72];      // [128 d][64+8 kpos]
  __shared__ u16 p_lds[4 * 16 * 72];// per-wave [16 qrow][64+8 kpos]

  const int tid  = threadIdx.x;
  const int lane = tid & 63;
  const int w    = tid >> 6;

  const int swz = xcd_swz(blockIdx.x, gridDim.x);
  const int nqb = F >> 6;
  const int qb   = swz % nqb;
  const int head = (swz / nqb) & 7;
  const int bc   = swz / (nqb * 8);

  const size_t rowbase = (size_t)bc * F * 3072;
  const float scale = 0.08838834764831845f;   // 1/sqrt(128)

  {
    const u16* qsrc = qkv + rowbase + (size_t)(qb * 64) * 3072 + head * 128;
    for (int it = tid; it < 1024; it += 256) {
      int r = it >> 4, s = it & 15;
      bf16x8 v = *(const bf16x8*)(qsrc + (size_t)r * 3072 + s * 8);
      bf16x8 o;
#pragma unroll
      for (int j = 0; j < 8; ++j) o[j] = (short)f2bf(bf2f((u16)v[j]) * scale);
      *(bf16x8*)(q_lds + r * 136 + s * 8) = o;
    }
  }

  f32x4 o_acc[8] = {};
  float m_run = -INFINITY, l_run = 0.f;
  const int qr = lane & 15;
  const int g4 = lane >> 4;

  const int nkb = F >> 6;
  for (int kb = 0; kb < nkb; ++kb) {
    __syncthreads();
    const u16* ksrc = qkv + rowbase + (size_t)(kb * 64) * 3072 + 1024 + head * 128;
    const u16* vsrc = qkv + rowbase + (size_t)(kb * 64) * 3072 + 2048 + head * 128;
    for (int it = tid; it < 1024; it += 256) {
      int r = it >> 4, s = it & 15;
      *(bf16x8*)(k_lds + r * 136 + s * 8) = *(const bf16x8*)(ksrc + (size_t)r * 3072 + s * 8);
      bf16x8 v = *(const bf16x8*)(vsrc + (size_t)r * 3072 + s * 8);
      int d0 = s * 8;
#pragma unroll
      for (int j = 0; j < 8; ++j) vT[(d0 + j) * 72 + r] = (u16)v[j];
    }
    __syncthreads();

    f32x4 sa[4] = {};
#pragma unroll
    for (int kk = 0; kk < 4; ++kk) {
      bf16x8 bq = *(const bf16x8*)(q_lds + (w * 16 + qr) * 136 + kk * 32 + 8 * g4);
#pragma unroll
      for (int f = 0; f < 4; ++f) {
        bf16x8 ak = *(const bf16x8*)(k_lds + (f * 16 + qr) * 136 + kk * 32 + 8 * g4);
        sa[f] = __builtin_amdgcn_mfma_f32_16x16x32_bf16(ak, bq, sa[f], 0, 0, 0);
      }
    }

    float tmax = -INFINITY;
#pragma unroll
    for (int f = 0; f < 4; ++f)
#pragma unroll
      for (int rr = 0; rr < 4; ++rr) tmax = fmaxf(tmax, sa[f][rr]);
    tmax = fmaxf(tmax, __shfl_xor(tmax, 16));
    tmax = fmaxf(tmax, __shfl_xor(tmax, 32));
    float mnew  = fmaxf(m_run, tmax);
    float alpha = __expf(m_run - mnew);
    float psum  = 0.f;
#pragma unroll
    for (int f = 0; f < 4; ++f) {
      u16 pp[4];
#pragma unroll
      for (int rr = 0; rr < 4; ++rr) {
        float p = __expf(sa[f][rr] - mnew);
        psum += p;
        pp[rr] = f2bf(p);
      }
      uint2 u;
      u.x = (u32)pp[0] | ((u32)pp[1] << 16);
      u.y = (u32)pp[2] | ((u32)pp[3] << 16);
      *(uint2*)(p_lds + w * 1152 + qr * 72 + f * 16 + g4 * 4) = u;
    }
    psum += __shfl_xor(psum, 16);
    psum += __shfl_xor(psum, 32);
    l_run = l_run * alpha + psum;
    m_run = mnew;

#pragma unroll
    for (int rr = 0; rr < 4; ++rr) {
      float ar = __shfl(alpha, g4 * 4 + rr);
#pragma unroll
      for (int g = 0; g < 8; ++g) o_acc[g][rr] *= ar;
    }

#pragma unroll
    for (int kk2 = 0; kk2 < 2; ++kk2) {
      bf16x8 pa = *(const bf16x8*)(p_lds + w * 1152 + qr * 72 + kk2 * 32 + 8 * g4);
#pragma unroll
      for (int g = 0; g < 8; ++g) {
        bf16x8 vb = *(const bf16x8*)(vT + (g * 16 + qr) * 72 + kk2 * 32 + 8 * g4);
        o_acc[g] = __builtin_amdgcn_mfma_f32_16x16x32_bf16(pa, vb, o_acc[g], 0, 0, 0);
      }
    }
  }

  float linv = 1.f / l_run;
#pragma unroll
  for (int rr = 0; rr < 4; ++rr) {
    float lr = __shfl(linv, g4 * 4 + rr);
    size_t row = (size_t)bc * F + qb * 64 + w * 16 + g4 * 4 + rr;
#pragma unroll
    for (int g = 0; g < 8; ++g)
      o_out[row * 1024 + head * 128 + g * 16 + qr] = f2bf(o_acc[g][rr] * lr);
  }
}

// ---------------------------------------------------------------------------
__global__ __launch_bounds__(256) void ln_stats(const u16* __restrict__ proj,
                                                float2* __restrict__ stats) {
  int row  = blockIdx.x * 4 + (threadIdx.x >> 6);
  int lane = threadIdx.x & 63;
  const u16* p = proj + (size_t)row * 1024;
  float s = 0.f, s2 = 0.f;
#pragma unroll
  for (int i = 0; i < 2; ++i) {
    bf16x8 v = *(const bf16x8*)(p + (lane + i * 64) * 8);
#pragma unroll
    for (int j = 0; j < 8; ++j) { float f = bf2f((u16)v[j]); s += f; s2 += f * f; }
  }
#pragma unroll
  for (int m = 1; m < 64; m <<= 1) { s += __shfl_xor(s, m); s2 += __shfl_xor(s2, m); }
  if (lane == 0) {
    float mu  = s * (1.f / 1024.f);
    float var = s2 * (1.f / 1024.f) - mu * mu;
    stats[row] = make_float2(mu, rsqrtf(var + 1e-5f));
  }
}

__global__ __launch_bounds__(256) void ln_accum(const u16* __restrict__ proj,
                                                const float2* __restrict__ stats,
                                                const float* __restrict__ g,
                                                const float* __restrict__ beta,
                                                float* __restrict__ dp, int F, int b0) {
  int d  = blockIdx.x * 256 + threadIdx.x;
  int bc = blockIdx.z;
  int f0 = blockIdx.y * 64;
  const u16* base = proj + ((size_t)(bc * F + f0)) * 1024 + d;
  const float2* st = stats + bc * F + f0;
  float acc = 0.f;
  for (int f = 0; f < 64; ++f) {
    float2 s = st[f];
    acc += (bf2f(base[(size_t)f * 1024]) - s.x) * s.y;
  }
  acc = acc * g[d] + 64.f * beta[d];
  atomicAdd(&dp[(size_t)(b0 + bc) * 1024 + d], acc);
}

__global__ __launch_bounds__(256) void cosine_sig(const float* __restrict__ dp,
                                                  const float* __restrict__ tp,
                                                  float* __restrict__ out) {
  __shared__ float red[3][4];
  int b = blockIdx.x;
  int tid = threadIdx.x, lane = tid & 63, w = tid >> 6;
  float dot = 0.f, n1 = 0.f, n2 = 0.f;
  for (int i = tid; i < 1024; i += 256) {
    float a = dp[(size_t)b * 1024 + i], c = tp[(size_t)b * 1024 + i];
    dot += a * c; n1 += a * a; n2 += c * c;
  }
#pragma unroll
  for (int m = 1; m < 64; m <<= 1) {
    dot += __shfl_xor(dot, m); n1 += __shfl_xor(n1, m); n2 += __shfl_xor(n2, m);
  }
  if (lane == 0) { red[0][w] = dot; red[1][w] = n1; red[2][w] = n2; }
  __syncthreads();
  if (tid == 0) {
    dot = red[0][0] + red[0][1] + red[0][2] + red[0][3];
    n1  = red[1][0] + red[1][1] + red[1][2] + red[1][3];
    n2  = red[2][0] + red[2][1] + red[2][2] + red[2][3];
    float denom = fmaxf(sqrtf(n1) * sqrtf(n2), 1e-8f);
    out[b] = 1.f / (1.f + __expf(-dot / denom));
  }
}

// ---------------------------------------------------------------------------
extern "C" void kernel_launch(void* const* d_in, const int* in_sizes, int n_in,
                              void* d_out, int out_size, void* d_ws, size_t ws_size,
                              hipStream_t stream) {
  const float* drug   = (const float*)d_in[0];
  const float* target = (const float*)d_in[1];

  char* p = (char*)d_ws;
  auto alloc = [&](size_t bytes) -> char* {
    char* r = p; p += (bytes + 255) & ~(size_t)255; return r;
  };

  u16* w_in_d  = (u16*)alloc((size_t)3072 * 1024 * 2);
  u16* w_out_d = (u16*)alloc((size_t)1024 * 1024 * 2);
  u16* w_in_t  = (u16*)alloc((size_t)3072 * 1024 * 2);
  u16* w_out_t = (u16*)alloc((size_t)1024 * 1024 * 2);
  float* dp    = (float*)alloc((size_t)2 * 128 * 1024 * 4);
  float* tp    = dp + 128 * 1024;

  size_t fixed = (size_t)(p - (char*)d_ws);
  size_t per = (size_t)256 * 1024 * 2 * 3
             + (size_t)256 * 3072 * 2
             + (size_t)256 * 8 + 2048;
  int Bc = 8;
  if      (fixed + 128 * per <= ws_size) Bc = 128;
  else if (fixed +  64 * per <= ws_size) Bc = 64;
  else if (fixed +  32 * per <= ws_size) Bc = 32;
  else if (fixed +  16 * per <= ws_size) Bc = 16;

  u16* hbuf    = (u16*)alloc((size_t)Bc * 256 * 1024 * 2);
  u16* qkvbuf  = (u16*)alloc((size_t)Bc * 256 * 3072 * 2);
  u16* obuf    = (u16*)alloc((size_t)Bc * 256 * 1024 * 2);
  u16* projbuf = (u16*)alloc((size_t)Bc * 256 * 1024 * 2);
  float2* statsb = (float2*)alloc((size_t)Bc * 256 * 8);

  cvt_bf16<<<1536, 256, 0, stream>>>((const float*)d_in[4],  w_in_d,  3072 * 128);
  cvt_bf16<<<512,  256, 0, stream>>>((const float*)d_in[6],  w_out_d, 1024 * 128);
  cvt_bf16<<<1536, 256, 0, stream>>>((const float*)d_in[12], w_in_t,  3072 * 128);
  cvt_bf16<<<512,  256, 0, stream>>>((const float*)d_in[14], w_out_t, 1024 * 128);
  hipMemsetAsync(dp, 0, (size_t)2 * 128 * 1024 * 4, stream);

  for (int br = 0; br < 2; ++br) {
    const int F = br ? 128 : 256, logF = br ? 7 : 8, xstride = br ? 1024 : 2048;
    const float* x    = br ? target : drug;
    const float* W    = (const float*)d_in[br ? 10 : 2];
    const float* Wb   = (const float*)d_in[br ? 11 : 3];
    u16*         win  = br ? w_in_t : w_in_d;
    const float* inb  = (const float*)d_in[br ? 13 : 5];
    u16*         wout = br ? w_out_t : w_out_d;
    const float* outb = (const float*)d_in[br ? 15 : 7];
    const float* gg   = (const float*)d_in[br ? 16 : 8];
    const float* bb   = (const float*)d_in[br ? 17 : 9];
    float*       accp = br ? tp : dp;

    for (int b0 = 0; b0 < 128; b0 += Bc) {
      const int Mr = Bc * F;
      hgen<<<Mr * 128 / 256, 256, 0, stream>>>(x, W, Wb, hbuf, F, logF, b0, xstride, Mr * 128);
      gemm_ph<<<dim3(3072 / 128, Mr / 256), 512, 0, stream>>>(hbuf, win, inb, qkvbuf, Mr, 3072, 1024);
      attn<<<(F / 64) * 8 * Bc, 256, 0, stream>>>(qkvbuf, obuf, F);
      gemm_ph<<<dim3(1024 / 128, Mr / 256), 512, 0, stream>>>(obuf, wout, outb, projbuf, Mr, 1024, 1024);
      ln_stats<<<Mr / 4, 256, 0, stream>>>(projbuf, statsb);
      ln_accum<<<dim3(4, F / 64, Bc), 256, 0, stream>>>(projbuf, statsb, gg, bb, accp, F, b0);
    }
  }
  cosine_sig<<<128, 256, 0, stream>>>(dp, tp, (float*)d_out);
}